// Round 2
// baseline (301.409 us; speedup 1.0000x reference)
//
#include <hip/hip_runtime.h>
#include <hip/hip_bf16.h>
#include <math.h>

#define B_SZ   1024
#define NROW   2048      // 2B
#define D_K    16384     // 128*128
#define SPLIT  8
#define KSEG   (D_K / SPLIT)   // 2048
#define NTILE  16
#define NPAIR  136
#define NSUB   8               // loss sub-blocks per tile
#define NPT    (NPAIR * NSUB)  // 1088
// fp8 rows scaled by 16 each => sim holds 256 * true_sim.
#define TEMP_SIM (2.0f / 256.0f)

typedef float f32x4 __attribute__((ext_vector_type(4)));
typedef long  i64;

typedef __attribute__((address_space(1))) unsigned int GU32;
typedef __attribute__((address_space(3))) unsigned int LU32;

__device__ __forceinline__ void async16(const void* g, void* l) {
  __builtin_amdgcn_global_load_lds((GU32*)(g), (LU32*)(l), 16, 0, 0);
}

// ---------------------------------------------------------------------------
// Kernel 1: per-row normalize -> fp8 e4m3 (x16) rn[2048][16384]; zero sim/rsum.
// ---------------------------------------------------------------------------
__global__ __launch_bounds__(512) void norm_kernel(
    const float* __restrict__ emb_i, const float* __restrict__ emb_j,
    unsigned char* __restrict__ rn, float* __restrict__ sim,
    float* __restrict__ rsum, unsigned int* __restrict__ cnt)
{
  const int b = blockIdx.x;
  const int t = threadIdx.x;
  const int c = t & 31;        // column group (4 cols)
  const int g = t >> 5;        // row group (8 rows), 0..15

  ((f32x4*)sim)[(size_t)b * 512 + t] = (f32x4){0.f, 0.f, 0.f, 0.f};
  if (b == 0) {
    for (int k = t; k < NROW; k += 512) rsum[k] = 0.f;
    if (t == 0) *cnt = 0u;
  }

  const float* src = (b < B_SZ) ? (emb_i + (size_t)b * D_K)
                                : (emb_j + (size_t)(b - B_SZ) * D_K);

  f32x4 vals[8];
  f32x4 ss = (f32x4){0.f, 0.f, 0.f, 0.f};
#pragma unroll
  for (int mm = 0; mm < 8; ++mm) {
    f32x4 v = *(const f32x4*)(src + (size_t)(g * 8 + mm) * 128 + c * 4);
    vals[mm] = v;
    ss += v * v;
  }

  __shared__ f32x4 part[16][32];
  part[g][c] = ss;
  __syncthreads();
  f32x4 css = part[0][c];
#pragma unroll
  for (int gg = 1; gg < 16; ++gg) css += part[gg][c];

  f32x4 mcn, colz2;
#pragma unroll
  for (int k = 0; k < 4; ++k) {
    mcn[k] = fmaxf(sqrtf(css[k]), 1e-12f);
    colz2[k] = css[k] / (mcn[k] * mcn[k]);
  }
  float s = colz2[0] + colz2[1] + colz2[2] + colz2[3];
#pragma unroll
  for (int off = 1; off < 64; off <<= 1) s += __shfl_xor(s, off);
  const float rowfac = fmaxf(sqrtf(0.5f * s), 1e-8f);

  f32x4 scale;
#pragma unroll
  for (int k = 0; k < 4; ++k) scale[k] = 16.0f / (mcn[k] * rowfac);

  unsigned char* dst = rn + (size_t)b * D_K;
#pragma unroll
  for (int mm = 0; mm < 8; ++mm) {
    f32x4 sv = vals[mm] * scale;
    int p = 0;
    p = __builtin_amdgcn_cvt_pk_fp8_f32(sv[0], sv[1], p, false);
    p = __builtin_amdgcn_cvt_pk_fp8_f32(sv[2], sv[3], p, true);
    *(int*)(dst + (size_t)(g * 8 + mm) * 128 + c * 4) = p;
  }
}

// ---------------------------------------------------------------------------
// Kernel 2: sim(upper) += rn @ rn^T. fp8 MFMA, 128x128 tile, BK=64,
// double-buffered at the SAME 32 KB LDS as the single-buffer version
// (2 x (8KB A + 8KB B)). Counted s_waitcnt vmcnt(4): the 4 prefetch
// global_load_lds stay in flight across both barriers; no vmcnt(0) drain
// in the main loop (last iter peeled). Row-XOR chunk swizzle over 4
// chunks/row: fragment ds_read_b64 banks = (col&1)*16 + 4*chunk + 2*(quad&1)
// -> only col vs col+8 alias (2-way, free). Grid (SPLIT, 136): XCD =
// linear%8 owns one K-segment -> 4 MB L2-resident.
// ---------------------------------------------------------------------------
__global__ __launch_bounds__(256) void gemm_sim_kernel(
    const unsigned char* __restrict__ rn, float* __restrict__ sim)
{
  int idx = blockIdx.y, tI = 0, rem = NTILE;
  while (idx >= rem) { idx -= rem; --rem; ++tI; }
  const int tJ = tI + idx;
  const bool diag = (tI == tJ);

  const int kBase = blockIdx.x * KSEG;
  const int t    = threadIdx.x;
  const int lane = t & 63;
  const int wave = t >> 6;
  const int wm = wave >> 1, wn = wave & 1;
  const int quad = lane >> 4, col = lane & 15;

  __shared__ __align__(16) unsigned char As[2][128 * 64];  // 2 x 8 KB
  __shared__ __align__(16) unsigned char Bs[2][128 * 64];  // 2 x 8 KB

  // staging: instr i stages rows 64i..64i+63. thread t -> row 64i+(t>>2),
  // global 16B chunk gc=(t&3)^(row&3) stored at LDS chunk t&3 (lds off
  // i*4096 + t*16, linear in t as global_load_lds requires).
  const int srow = t >> 2;
  const int gc   = (t & 3) ^ (srow & 3);
  const unsigned char* aGb = rn + (size_t)(tI * 128 + srow) * D_K + kBase + gc * 16;
  const unsigned char* bGb = rn + (size_t)(tJ * 128 + srow) * D_K + kBase + gc * 16;

  f32x4 acc[4][4];
#pragma unroll
  for (int mi = 0; mi < 4; ++mi)
#pragma unroll
    for (int ni = 0; ni < 4; ++ni)
      acc[mi][ni] = (f32x4){0.f, 0.f, 0.f, 0.f};

  // prologue: stage K-step 0 into buffer 0 (4 loads/wave in flight)
#pragma unroll
  for (int i = 0; i < 2; ++i) {
    async16(aGb + (size_t)(64 * i) * D_K, &As[0][i * 4096 + t * 16]);
    async16(bGb + (size_t)(64 * i) * D_K, &Bs[0][i * 4096 + t * 16]);
  }

  int cur = 0;
  for (int k0 = 0; k0 < KSEG; k0 += 64) {
    const int nxt = cur ^ 1;
    if (k0 + 64 < KSEG) {
      // prefetch next K-step; vmcnt(4) waits only for the 4 older loads
      // (= buf[cur]) -- prefetch stays in flight across the barriers.
#pragma unroll
      for (int i = 0; i < 2; ++i) {
        async16(aGb + (size_t)(64 * i) * D_K + k0 + 64,
                &As[nxt][i * 4096 + t * 16]);
        async16(bGb + (size_t)(64 * i) * D_K + k0 + 64,
                &Bs[nxt][i * 4096 + t * 16]);
      }
      asm volatile("s_waitcnt vmcnt(4)" ::: "memory");
    } else {
      asm volatile("s_waitcnt vmcnt(0)" ::: "memory");
    }
    __builtin_amdgcn_s_barrier();   // all waves: buf[cur] fully staged

#pragma unroll
    for (int h = 0; h < 2; ++h) {
      // lane wants global k-bytes [32h + quad*8, +8) of its row:
      // chunk g = 2h + (quad>>1) in 0..3, stored at LDS chunk g ^ (row&3),
      // row&3 = col&3.
      const int off = ((2 * h + (quad >> 1)) ^ (col & 3)) * 16 + (quad & 1) * 8;
      i64 af[4], bf[4];
#pragma unroll
      for (int mi = 0; mi < 4; ++mi)
        af[mi] = *(const i64*)(&As[cur][(wm * 64 + mi * 16 + col) * 64 + off]);
#pragma unroll
      for (int ni = 0; ni < 4; ++ni)
        bf[ni] = *(const i64*)(&Bs[cur][(wn * 64 + ni * 16 + col) * 64 + off]);
#pragma unroll
      for (int mi = 0; mi < 4; ++mi)
#pragma unroll
        for (int ni = 0; ni < 4; ++ni)
          acc[mi][ni] = __builtin_amdgcn_mfma_f32_16x16x32_fp8_fp8(
              af[mi], bf[ni], acc[mi][ni], 0, 0, 0);
    }

    // all waves' ds_reads of buf[cur] have returned (each is consumed by an
    // MFMA above, forcing lgkmcnt waits) -> next iter may overwrite it.
    __builtin_amdgcn_s_barrier();
    cur = nxt;
  }

  // C/D layout: col=lane&15, row=quad*4+reg. Diag tiles: only j >= i stored.
  const int iB = tI * 128 + wm * 64;
  const int jB = tJ * 128 + wn * 64;
#pragma unroll
  for (int mi = 0; mi < 4; ++mi) {
#pragma unroll
    for (int reg = 0; reg < 4; ++reg) {
      const int i = iB + mi * 16 + quad * 4 + reg;
#pragma unroll
      for (int ni = 0; ni < 4; ++ni) {
        const int j = jB + ni * 16 + col;
        if (!diag || j >= i)
          atomicAdd(&sim[(size_t)i * NROW + j], acc[mi][ni][reg]);
      }
    }
  }
}

// ---------------------------------------------------------------------------
// Kernel 3: tile exp-sum (upper tiles, symmetric scatter) + fused finalize.
// Grid (NSUB, NPAIR) = 1088 blocks (was 136: half the CUs sat idle).
// Each block: 16 rows x 128 cols; 16 lanes/row; row-reduce via 4 shfl_xor;
// column sums via 8 KB LDS transpose + 1 atomic/column.
// ---------------------------------------------------------------------------
__global__ __launch_bounds__(256) void loss_tile_kernel(
    const float* __restrict__ sim, float* __restrict__ rsum,
    unsigned int* __restrict__ cnt, float* __restrict__ out)
{
  int idx = blockIdx.y, tI = 0, rem = NTILE;
  while (idx >= rem) { idx -= rem; --rem; ++tI; }
  const int tJ = tI + idx;
  const bool diag = (tI == tJ);

  const int t  = threadIdx.x;
  const int r  = t >> 4;          // row within sub-block, 0..15
  const int cg = t & 15;          // column group (8 cols), 0..15
  const int gi = tI * 128 + blockIdx.x * 16 + r;
  const int jb = tJ * 128 + cg * 8;

  const f32x4 v0 = *(const f32x4*)(sim + (size_t)gi * NROW + jb);
  const f32x4 v1 = *(const f32x4*)(sim + (size_t)gi * NROW + jb + 4);

  float e[8];
  float rowp = 0.f;
#pragma unroll
  for (int k = 0; k < 4; ++k) {
    e[k] = __expf(TEMP_SIM * v0[k]);
    if (diag && (jb + k <= gi)) e[k] = 0.f;
    rowp += e[k];
  }
#pragma unroll
  for (int k = 0; k < 4; ++k) {
    e[4 + k] = __expf(TEMP_SIM * v1[k]);
    if (diag && (jb + 4 + k <= gi)) e[4 + k] = 0.f;
    rowp += e[4 + k];
  }

  // reduce across the 16 lanes of this row
#pragma unroll
  for (int off = 1; off < 16; off <<= 1) rowp += __shfl_xor(rowp, off);
  if (cg == 0) atomicAdd(&rsum[gi], rowp);

  __shared__ float colacc[16][128];
  *(f32x4*)&colacc[r][cg * 8]     = (f32x4){e[0], e[1], e[2], e[3]};
  *(f32x4*)&colacc[r][cg * 8 + 4] = (f32x4){e[4], e[5], e[6], e[7]};
  __syncthreads();
  if (t < 128) {
    float s = 0.f;
#pragma unroll
    for (int q = 0; q < 16; ++q) s += colacc[q][t];
    atomicAdd(&rsum[tJ * 128 + t], s);
  }

  __syncthreads();
  __shared__ bool last;
  if (t == 0) {
    __threadfence();
    last = (atomicAdd(cnt, 1u) == NPT - 1);
  }
  __syncthreads();
  if (!last) return;

  float s = 0.f;
  for (int i = t; i < NROW; i += 256) {
    const int jp = (i < B_SZ) ? i + B_SZ : i - B_SZ;
    const float pos = (jp >= i) ? sim[(size_t)i * NROW + jp]
                                : sim[(size_t)jp * NROW + i];
    const float rs = atomicAdd(&rsum[i], 0.f);
    s += logf(rs) - TEMP_SIM * pos;
  }
#pragma unroll
  for (int off = 1; off < 64; off <<= 1) s += __shfl_xor(s, off);
  __shared__ float rr[4];
  if ((t & 63) == 0) rr[t >> 6] = s;
  __syncthreads();
  if (t == 0) out[0] = (rr[0] + rr[1] + rr[2] + rr[3]) * (1.0f / NROW);
}

extern "C" void kernel_launch(void* const* d_in, const int* in_sizes, int n_in,
                              void* d_out, int out_size, void* d_ws, size_t ws_size,
                              hipStream_t stream) {
  const float* emb_i = (const float*)d_in[0];
  const float* emb_j = (const float*)d_in[1];
  float* out = (float*)d_out;

  char* ws = (char*)d_ws;
  unsigned char* rn = (unsigned char*)ws;                 // 32 MB (fp8)
  float* sim  = (float*)(ws + (size_t)NROW * D_K);        // 16 MB
  float* rsum = sim + (size_t)NROW * NROW;                // 8 KB
  unsigned int* cnt = (unsigned int*)(rsum + NROW);

  norm_kernel<<<dim3(NROW), dim3(512), 0, stream>>>(emb_i, emb_j, rn, sim, rsum, cnt);
  gemm_sim_kernel<<<dim3(SPLIT, NPAIR), dim3(256), 0, stream>>>(rn, sim);
  loss_tile_kernel<<<dim3(NSUB, NPAIR), dim3(256), 0, stream>>>(sim, rsum, cnt, out);
}

// Round 3
// 286.601 us; speedup vs baseline: 1.0517x; 1.0517x over previous
//
#include <hip/hip_runtime.h>
#include <hip/hip_bf16.h>
#include <math.h>

#define B_SZ   1024
#define NROW   2048      // 2B
#define D_K    16384     // 128*128
#define SPLIT  8
#define KSEG   (D_K / SPLIT)   // 2048
#define NTILE  16
#define NPAIR  136
#define NSUB   8               // loss sub-blocks per tile
#define NPT    (NPAIR * NSUB)  // 1088
// fp8 rows scaled by 16 each => sim holds 256 * true_sim.
#define TEMP_SIM (2.0f / 256.0f)

typedef float f32x4 __attribute__((ext_vector_type(4)));
typedef long  i64;
typedef long  i64x2 __attribute__((ext_vector_type(2)));

typedef __attribute__((address_space(1))) unsigned int GU32;
typedef __attribute__((address_space(3))) unsigned int LU32;

__device__ __forceinline__ void async16(const void* g, void* l) {
  __builtin_amdgcn_global_load_lds((GU32*)(g), (LU32*)(l), 16, 0, 0);
}

// ---------------------------------------------------------------------------
// rn GLOBAL layout (pre-swizzled; rn is private workspace, we own the format):
// row r is split into 64B K-segments. Within a segment, 8B subchunk s
// (k-bytes [8s,8s+8)) with q=s&3, h=s>>2 is stored at byte
// (q ^ ((r>>1)&3))*16 + h*8. Then in gemm:
//  - staging is PURE linear global_load_lds (16B chunks in stored order);
//  - lane (col,quad) reads ONE ds_read_b128 at row*64+(quad^((row>>1)&3))*16
//    whose 8B halves are the h=0 / h=1 MFMA operands;
//  - bank math per 16-lane phase: block index bijective over {0..3} via
//    (col>>1)&3, row parity gives +16 dwords -> all 32 banks exactly once.
//    ZERO LDS read conflicts (r2's 26.7M were 4 lanes/bank within phase).
// ---------------------------------------------------------------------------

// ---------------------------------------------------------------------------
// Kernel 1: per-row normalize -> fp8 e4m3 (x16) rn[2048][16384]; zero sim/rsum.
// Writes rn in the block-permuted global layout described above.
// ---------------------------------------------------------------------------
__global__ __launch_bounds__(512) void norm_kernel(
    const float* __restrict__ emb_i, const float* __restrict__ emb_j,
    unsigned char* __restrict__ rn, float* __restrict__ sim,
    float* __restrict__ rsum, unsigned int* __restrict__ cnt)
{
  const int b = blockIdx.x;
  const int t = threadIdx.x;
  const int c = t & 31;        // column group (4 cols)
  const int g = t >> 5;        // row group (8 rows), 0..15

  ((f32x4*)sim)[(size_t)b * 512 + t] = (f32x4){0.f, 0.f, 0.f, 0.f};
  if (b == 0) {
    for (int k = t; k < NROW; k += 512) rsum[k] = 0.f;
    if (t == 0) *cnt = 0u;
  }

  const float* src = (b < B_SZ) ? (emb_i + (size_t)b * D_K)
                                : (emb_j + (size_t)(b - B_SZ) * D_K);

  f32x4 vals[8];
  f32x4 ss = (f32x4){0.f, 0.f, 0.f, 0.f};
#pragma unroll
  for (int mm = 0; mm < 8; ++mm) {
    f32x4 v = *(const f32x4*)(src + (size_t)(g * 8 + mm) * 128 + c * 4);
    vals[mm] = v;
    ss += v * v;
  }

  __shared__ f32x4 part[16][32];
  part[g][c] = ss;
  __syncthreads();
  f32x4 css = part[0][c];
#pragma unroll
  for (int gg = 1; gg < 16; ++gg) css += part[gg][c];

  f32x4 mcn, colz2;
#pragma unroll
  for (int k = 0; k < 4; ++k) {
    mcn[k] = fmaxf(sqrtf(css[k]), 1e-12f);
    colz2[k] = css[k] / (mcn[k] * mcn[k]);
  }
  float s = colz2[0] + colz2[1] + colz2[2] + colz2[3];
#pragma unroll
  for (int off = 1; off < 64; off <<= 1) s += __shfl_xor(s, off);
  const float rowfac = fmaxf(sqrtf(0.5f * s), 1e-8f);

  f32x4 scale;
#pragma unroll
  for (int k = 0; k < 4; ++k) scale[k] = 16.0f / (mcn[k] * rowfac);

  unsigned char* dst = rn + (size_t)b * D_K;
  const int wsel = (b >> 1) & 3;
#pragma unroll
  for (int mm = 0; mm < 8; ++mm) {
    f32x4 sv = vals[mm] * scale;
    int p = 0;
    p = __builtin_amdgcn_cvt_pk_fp8_f32(sv[0], sv[1], p, false);
    p = __builtin_amdgcn_cvt_pk_fp8_f32(sv[2], sv[3], p, true);
    // original k-byte index of this int: k = (g*8+mm)*128 + c*4
    const int k = (g * 8 + mm) * 128 + c * 4;
    // permute within the 64B segment: q=(k>>3)&3, h=(k>>5)&1
    const int nk = (k & ~63) | ((((k >> 3) & 3) ^ wsel) << 4)
                 | (((k >> 5) & 1) << 3) | (k & 7);
    *(int*)(dst + nk) = p;
  }
}

// ---------------------------------------------------------------------------
// Kernel 2: sim(upper) += rn @ rn^T. fp8 MFMA, 128x128 tile, BK=64,
// double-buffered in 32 KB LDS, counted s_waitcnt vmcnt(4) (prefetch stays
// in flight across barriers; no vmcnt(0) in the main loop). rn's global
// pre-swizzle makes staging linear and fragment ds_read_b128 conflict-free.
// Grid (SPLIT, 136): XCD = linear%8 owns one K-segment -> L2-resident.
// ---------------------------------------------------------------------------
__global__ __launch_bounds__(256) void gemm_sim_kernel(
    const unsigned char* __restrict__ rn, float* __restrict__ sim)
{
  int idx = blockIdx.y, tI = 0, rem = NTILE;
  while (idx >= rem) { idx -= rem; --rem; ++tI; }
  const int tJ = tI + idx;
  const bool diag = (tI == tJ);

  const int kBase = blockIdx.x * KSEG;
  const int t    = threadIdx.x;
  const int lane = t & 63;
  const int wave = t >> 6;
  const int wm = wave >> 1, wn = wave & 1;
  const int quad = lane >> 4, col = lane & 15;

  __shared__ __align__(16) unsigned char As[2][128 * 64];  // 2 x 8 KB
  __shared__ __align__(16) unsigned char Bs[2][128 * 64];  // 2 x 8 KB

  // staging: instr i stages rows 64i..64i+63. thread t -> row 64i+(t>>2),
  // stored 16B chunk t&3 (global already permuted) -> LDS i*4096 + t*16.
  const int srow = t >> 2;
  const unsigned char* aGb = rn + (size_t)(tI * 128 + srow) * D_K + kBase + (t & 3) * 16;
  const unsigned char* bGb = rn + (size_t)(tJ * 128 + srow) * D_K + kBase + (t & 3) * 16;

  f32x4 acc[4][4];
#pragma unroll
  for (int mi = 0; mi < 4; ++mi)
#pragma unroll
    for (int ni = 0; ni < 4; ++ni)
      acc[mi][ni] = (f32x4){0.f, 0.f, 0.f, 0.f};

  // fragment-read block index: quad ^ ((row>>1)&3), row&15 = col
  const int rblk = (quad ^ ((col >> 1) & 3)) * 16;

  // prologue: stage K-step 0 into buffer 0 (4 loads/wave in flight)
#pragma unroll
  for (int i = 0; i < 2; ++i) {
    async16(aGb + (size_t)(64 * i) * D_K, &As[0][i * 4096 + t * 16]);
    async16(bGb + (size_t)(64 * i) * D_K, &Bs[0][i * 4096 + t * 16]);
  }

  int cur = 0;
  for (int k0 = 0; k0 < KSEG; k0 += 64) {
    const int nxt = cur ^ 1;
    if (k0 + 64 < KSEG) {
      // prefetch next K-step; vmcnt(4) waits only for the 4 older loads
      // (= buf[cur]) -- prefetch stays in flight across the barriers.
#pragma unroll
      for (int i = 0; i < 2; ++i) {
        async16(aGb + (size_t)(64 * i) * D_K + k0 + 64,
                &As[nxt][i * 4096 + t * 16]);
        async16(bGb + (size_t)(64 * i) * D_K + k0 + 64,
                &Bs[nxt][i * 4096 + t * 16]);
      }
      asm volatile("s_waitcnt vmcnt(4)" ::: "memory");
    } else {
      asm volatile("s_waitcnt vmcnt(0)" ::: "memory");
    }
    __builtin_amdgcn_s_barrier();   // all waves: buf[cur] fully staged

    // one b128 per fragment: halves are the h=0 / h=1 operands
    i64x2 av[4], bv[4];
#pragma unroll
    for (int mi = 0; mi < 4; ++mi)
      av[mi] = *(const i64x2*)(&As[cur][(wm * 64 + mi * 16 + col) * 64 + rblk]);
#pragma unroll
    for (int ni = 0; ni < 4; ++ni)
      bv[ni] = *(const i64x2*)(&Bs[cur][(wn * 64 + ni * 16 + col) * 64 + rblk]);

#pragma unroll
    for (int mi = 0; mi < 4; ++mi)
#pragma unroll
      for (int ni = 0; ni < 4; ++ni)
        acc[mi][ni] = __builtin_amdgcn_mfma_f32_16x16x32_fp8_fp8(
            av[mi][0], bv[ni][0], acc[mi][ni], 0, 0, 0);
#pragma unroll
    for (int mi = 0; mi < 4; ++mi)
#pragma unroll
      for (int ni = 0; ni < 4; ++ni)
        acc[mi][ni] = __builtin_amdgcn_mfma_f32_16x16x32_fp8_fp8(
            av[mi][1], bv[ni][1], acc[mi][ni], 0, 0, 0);

    // all waves' ds_reads of buf[cur] consumed by MFMAs above -> safe to
    // overwrite buf[cur] next iteration.
    __builtin_amdgcn_s_barrier();
    cur = nxt;
  }

  // C/D layout: col=lane&15, row=quad*4+reg. Diag tiles: only j >= i stored.
  const int iB = tI * 128 + wm * 64;
  const int jB = tJ * 128 + wn * 64;
#pragma unroll
  for (int mi = 0; mi < 4; ++mi) {
#pragma unroll
    for (int reg = 0; reg < 4; ++reg) {
      const int i = iB + mi * 16 + quad * 4 + reg;
#pragma unroll
      for (int ni = 0; ni < 4; ++ni) {
        const int j = jB + ni * 16 + col;
        if (!diag || j >= i)
          atomicAdd(&sim[(size_t)i * NROW + j], acc[mi][ni][reg]);
      }
    }
  }
}

// ---------------------------------------------------------------------------
// Kernel 3: tile exp-sum (upper tiles, symmetric scatter) + fused finalize.
// Grid (NSUB, NPAIR) = 1088 blocks; 16 rows x 128 cols per block.
// ---------------------------------------------------------------------------
__global__ __launch_bounds__(256) void loss_tile_kernel(
    const float* __restrict__ sim, float* __restrict__ rsum,
    unsigned int* __restrict__ cnt, float* __restrict__ out)
{
  int idx = blockIdx.y, tI = 0, rem = NTILE;
  while (idx >= rem) { idx -= rem; --rem; ++tI; }
  const int tJ = tI + idx;
  const bool diag = (tI == tJ);

  const int t  = threadIdx.x;
  const int r  = t >> 4;          // row within sub-block, 0..15
  const int cg = t & 15;          // column group (8 cols), 0..15
  const int gi = tI * 128 + blockIdx.x * 16 + r;
  const int jb = tJ * 128 + cg * 8;

  const f32x4 v0 = *(const f32x4*)(sim + (size_t)gi * NROW + jb);
  const f32x4 v1 = *(const f32x4*)(sim + (size_t)gi * NROW + jb + 4);

  float e[8];
  float rowp = 0.f;
#pragma unroll
  for (int k = 0; k < 4; ++k) {
    e[k] = __expf(TEMP_SIM * v0[k]);
    if (diag && (jb + k <= gi)) e[k] = 0.f;
    rowp += e[k];
  }
#pragma unroll
  for (int k = 0; k < 4; ++k) {
    e[4 + k] = __expf(TEMP_SIM * v1[k]);
    if (diag && (jb + 4 + k <= gi)) e[4 + k] = 0.f;
    rowp += e[4 + k];
  }

  // reduce across the 16 lanes of this row
#pragma unroll
  for (int off = 1; off < 16; off <<= 1) rowp += __shfl_xor(rowp, off);
  if (cg == 0) atomicAdd(&rsum[gi], rowp);

  __shared__ float colacc[16][128];
  *(f32x4*)&colacc[r][cg * 8]     = (f32x4){e[0], e[1], e[2], e[3]};
  *(f32x4*)&colacc[r][cg * 8 + 4] = (f32x4){e[4], e[5], e[6], e[7]};
  __syncthreads();
  if (t < 128) {
    float s = 0.f;
#pragma unroll
    for (int q = 0; q < 16; ++q) s += colacc[q][t];
    atomicAdd(&rsum[tJ * 128 + t], s);
  }

  __syncthreads();
  __shared__ bool last;
  if (t == 0) {
    __threadfence();
    last = (atomicAdd(cnt, 1u) == NPT - 1);
  }
  __syncthreads();
  if (!last) return;

  float s = 0.f;
  for (int i = t; i < NROW; i += 256) {
    const int jp = (i < B_SZ) ? i + B_SZ : i - B_SZ;
    const float pos = (jp >= i) ? sim[(size_t)i * NROW + jp]
                                : sim[(size_t)jp * NROW + i];
    const float rs = atomicAdd(&rsum[i], 0.f);
    s += logf(rs) - TEMP_SIM * pos;
  }
#pragma unroll
  for (int off = 1; off < 64; off <<= 1) s += __shfl_xor(s, off);
  __shared__ float rr[4];
  if ((t & 63) == 0) rr[t >> 6] = s;
  __syncthreads();
  if (t == 0) out[0] = (rr[0] + rr[1] + rr[2] + rr[3]) * (1.0f / NROW);
}

extern "C" void kernel_launch(void* const* d_in, const int* in_sizes, int n_in,
                              void* d_out, int out_size, void* d_ws, size_t ws_size,
                              hipStream_t stream) {
  const float* emb_i = (const float*)d_in[0];
  const float* emb_j = (const float*)d_in[1];
  float* out = (float*)d_out;

  char* ws = (char*)d_ws;
  unsigned char* rn = (unsigned char*)ws;                 // 32 MB (fp8)
  float* sim  = (float*)(ws + (size_t)NROW * D_K);        // 16 MB
  float* rsum = sim + (size_t)NROW * NROW;                // 8 KB
  unsigned int* cnt = (unsigned int*)(rsum + NROW);

  norm_kernel<<<dim3(NROW), dim3(512), 0, stream>>>(emb_i, emb_j, rn, sim, rsum, cnt);
  gemm_sim_kernel<<<dim3(SPLIT, NPAIR), dim3(256), 0, stream>>>(rn, sim);
  loss_tile_kernel<<<dim3(NSUB, NPAIR), dim3(256), 0, stream>>>(sim, rsum, cnt, out);
}

// Round 5
// 284.193 us; speedup vs baseline: 1.0606x; 1.0085x over previous
//
#include <hip/hip_runtime.h>
#include <hip/hip_bf16.h>
#include <math.h>

#define B_SZ   1024
#define NROW   2048      // 2B
#define D_K    16384     // 128*128
#define SPLIT  8
#define KSEG   (D_K / SPLIT)   // 2048
#define NTILE  16
#define NPAIR  136
#define HPAIR  68        // gemm split into 2 dispatches for rocprof visibility
// fp8 rows scaled by 16 each => sim holds 256 * true_sim.
#define TEMP_SIM (2.0f / 256.0f)

typedef float f32x4 __attribute__((ext_vector_type(4)));
typedef long  i64;
typedef long  i64x2 __attribute__((ext_vector_type(2)));

typedef __attribute__((address_space(1))) unsigned int GU32;
typedef __attribute__((address_space(3))) unsigned int LU32;

__device__ __forceinline__ void async16(const void* g, void* l) {
  __builtin_amdgcn_global_load_lds((GU32*)(g), (LU32*)(l), 16, 0, 0);
}

// ---------------------------------------------------------------------------
// rn GLOBAL layout (verified zero-conflict in r3): row r is split into 64B
// K-segments. Subchunk s (k-bytes [8s,8s+8)), q=s&3, h=s>>2 stored at byte
// (q ^ ((r>>1)&3))*16 + h*8. gemm stages each 64B segment as one LDS "plane"
// row (64B row stride); fragment read = ONE ds_read_b128 per (row, segment)
// at row*64 + (quad^((col>>1)&3))*16, halves = the two 32k MFMA operands.
// r3 measured SQ_LDS_BANK_CONFLICT == 0 with exactly this read pattern.
// ---------------------------------------------------------------------------

// ---------------------------------------------------------------------------
// Kernel 0: zero sim (16 MB). Separate dispatch so norm stays a pure
// attributable stream kernel.
// ---------------------------------------------------------------------------
__global__ __launch_bounds__(512) void zero_sim_kernel(float* __restrict__ sim)
{
  ((f32x4*)sim)[(size_t)blockIdx.x * 512 + threadIdx.x] =
      (f32x4){0.f, 0.f, 0.f, 0.f};
}

// ---------------------------------------------------------------------------
// Kernel 1: per-row normalize -> fp8 e4m3 (x16) rn[2048][16384] in the
// block-permuted global layout; zero rsum/cnt (block 0 only).
// ---------------------------------------------------------------------------
__global__ __launch_bounds__(512) void norm_kernel(
    const float* __restrict__ emb_i, const float* __restrict__ emb_j,
    unsigned char* __restrict__ rn,
    float* __restrict__ rsum, unsigned int* __restrict__ cnt)
{
  const int b = blockIdx.x;
  const int t = threadIdx.x;
  const int c = t & 31;        // column group (4 cols)
  const int g = t >> 5;        // row group (8 rows), 0..15

  if (b == 0) {
    for (int k = t; k < NROW; k += 512) rsum[k] = 0.f;
    if (t == 0) *cnt = 0u;
  }

  const float* src = (b < B_SZ) ? (emb_i + (size_t)b * D_K)
                                : (emb_j + (size_t)(b - B_SZ) * D_K);

  f32x4 vals[8];
  f32x4 ss = (f32x4){0.f, 0.f, 0.f, 0.f};
#pragma unroll
  for (int mm = 0; mm < 8; ++mm) {
    f32x4 v = *(const f32x4*)(src + (size_t)(g * 8 + mm) * 128 + c * 4);
    vals[mm] = v;
    ss += v * v;
  }

  __shared__ f32x4 part[16][32];
  part[g][c] = ss;
  __syncthreads();
  f32x4 css = part[0][c];
#pragma unroll
  for (int gg = 1; gg < 16; ++gg) css += part[gg][c];

  f32x4 mcn, colz2;
#pragma unroll
  for (int k = 0; k < 4; ++k) {
    mcn[k] = fmaxf(sqrtf(css[k]), 1e-12f);
    colz2[k] = css[k] / (mcn[k] * mcn[k]);
  }
  float s = colz2[0] + colz2[1] + colz2[2] + colz2[3];
#pragma unroll
  for (int off = 1; off < 64; off <<= 1) s += __shfl_xor(s, off);
  const float rowfac = fmaxf(sqrtf(0.5f * s), 1e-8f);

  f32x4 scale;
#pragma unroll
  for (int k = 0; k < 4; ++k) scale[k] = 16.0f / (mcn[k] * rowfac);

  unsigned char* dst = rn + (size_t)b * D_K;
  const int wsel = (b >> 1) & 3;
#pragma unroll
  for (int mm = 0; mm < 8; ++mm) {
    f32x4 sv = vals[mm] * scale;
    int p = 0;
    p = __builtin_amdgcn_cvt_pk_fp8_f32(sv[0], sv[1], p, false);
    p = __builtin_amdgcn_cvt_pk_fp8_f32(sv[2], sv[3], p, true);
    // original k-byte index of this int: k = (g*8+mm)*128 + c*4
    const int k = (g * 8 + mm) * 128 + c * 4;
    // permute within the 64B segment: q=(k>>3)&3, h=(k>>5)&1
    const int nk = (k & ~63) | ((((k >> 3) & 3) ^ wsel) << 4)
                 | (((k >> 5) & 1) << 3) | (k & 7);
    *(int*)(dst + nk) = p;
  }
}

// ---------------------------------------------------------------------------
// Kernel 2: sim(upper) += rn @ rn^T. fp8 MFMA, 128x128 tile, BK=128,
// r0's PROVEN drain structure (sync / 8x global_load_lds / sync / 64 MFMA,
// 16 iters) -- 2-phase pipelining measured slower 3 rounds running (m233:
// simple loops cap ~37%; 8-phase needs 256^2 tiles our grid can't fill).
// LDS: per matrix 2 planes (64B K-segments) x 128 rows x 64B = 16 KB;
// A+B = 32 KB. Fragment reads: 16x ds_read_b128/lane/K-tile, zero-conflict
// (r3-verified). Grid (SPLIT, HPAIR) x2 dispatches: XCD = linear%8 owns one
// K-segment; split dispatch halves expose norm/loss in rocprof top-5.
// ---------------------------------------------------------------------------
__global__ __launch_bounds__(256) void gemm_sim_kernel(
    const unsigned char* __restrict__ rn, float* __restrict__ sim, int pairBase)
{
  int idx = pairBase + blockIdx.y, tI = 0, rem = NTILE;
  while (idx >= rem) { idx -= rem; --rem; ++tI; }
  const int tJ = tI + idx;
  const bool diag = (tI == tJ);

  const int kBase = blockIdx.x * KSEG;
  const int t    = threadIdx.x;
  const int lane = t & 63;
  const int wave = t >> 6;
  const int wm = wave >> 1, wn = wave & 1;
  const int quad = lane >> 4, col = lane & 15;

  __shared__ __align__(16) unsigned char As[2][128 * 64];  // plane p = K-seg p
  __shared__ __align__(16) unsigned char Bs[2][128 * 64];

  // staging: instr (j,p) stages rows 64j..64j+63, segment p.
  // thread t -> row 64j+(t>>2), stored 16B chunk t&3 -> LDS plane p,
  // j*4096 + t*16 (lane-linear as global_load_lds requires).
  const int srow = t >> 2;
  const unsigned char* aGb = rn + (size_t)(tI * 128 + srow) * D_K + kBase + (t & 3) * 16;
  const unsigned char* bGb = rn + (size_t)(tJ * 128 + srow) * D_K + kBase + (t & 3) * 16;

  f32x4 acc[4][4];
#pragma unroll
  for (int mi = 0; mi < 4; ++mi)
#pragma unroll
    for (int ni = 0; ni < 4; ++ni)
      acc[mi][ni] = (f32x4){0.f, 0.f, 0.f, 0.f};

  // fragment-read 16B block: quad ^ ((row>>1)&3); row bits 1..2 come from col
  const int rblk = (quad ^ ((col >> 1) & 3)) * 16;

  for (int k0 = 0; k0 < KSEG; k0 += 128) {
    __syncthreads();   // previous compute done -> safe to overwrite
#pragma unroll
    for (int j = 0; j < 2; ++j)
#pragma unroll
      for (int p = 0; p < 2; ++p) {
        async16(aGb + (size_t)(64 * j) * D_K + k0 + p * 64,
                &As[p][j * 4096 + t * 16]);
        async16(bGb + (size_t)(64 * j) * D_K + k0 + p * 64,
                &Bs[p][j * 4096 + t * 16]);
      }
    __syncthreads();   // compiler emits vmcnt(0) drain before barrier

#pragma unroll
    for (int hh = 0; hh < 2; ++hh) {
      // one b128 per (row-fragment, segment): halves are k-steps 2hh, 2hh+1
      i64x2 av[4], bv[4];
#pragma unroll
      for (int mi = 0; mi < 4; ++mi)
        av[mi] = *(const i64x2*)(&As[hh][(wm * 64 + mi * 16 + col) * 64 + rblk]);
#pragma unroll
      for (int ni = 0; ni < 4; ++ni)
        bv[ni] = *(const i64x2*)(&Bs[hh][(wn * 64 + ni * 16 + col) * 64 + rblk]);

#pragma unroll
      for (int mi = 0; mi < 4; ++mi)
#pragma unroll
        for (int ni = 0; ni < 4; ++ni)
          acc[mi][ni] = __builtin_amdgcn_mfma_f32_16x16x32_fp8_fp8(
              av[mi][0], bv[ni][0], acc[mi][ni], 0, 0, 0);
#pragma unroll
      for (int mi = 0; mi < 4; ++mi)
#pragma unroll
        for (int ni = 0; ni < 4; ++ni)
          acc[mi][ni] = __builtin_amdgcn_mfma_f32_16x16x32_fp8_fp8(
              av[mi][1], bv[ni][1], acc[mi][ni], 0, 0, 0);
    }
  }

  // C/D layout: col=lane&15, row=quad*4+reg. Diag tiles: only j >= i stored.
  const int iB = tI * 128 + wm * 64;
  const int jB = tJ * 128 + wn * 64;
#pragma unroll
  for (int mi = 0; mi < 4; ++mi) {
#pragma unroll
    for (int reg = 0; reg < 4; ++reg) {
      const int i = iB + mi * 16 + quad * 4 + reg;
#pragma unroll
      for (int ni = 0; ni < 4; ++ni) {
        const int j = jB + ni * 16 + col;
        if (!diag || j >= i)
          atomicAdd(&sim[(size_t)i * NROW + j], acc[mi][ni][reg]);
      }
    }
  }
}

// ---------------------------------------------------------------------------
// Kernel 3: tile exp-sum (upper tiles, symmetric scatter) + fused finalize.
// r0's version (136 blocks, serial 16-step): measured 8 us FASTER in
// aggregate than the 1088-block variant (r0 vs r2/r3 algebra).
// ---------------------------------------------------------------------------
__global__ __launch_bounds__(256) void loss_tile_kernel(
    const float* __restrict__ sim, float* __restrict__ rsum,
    unsigned int* __restrict__ cnt, float* __restrict__ out)
{
  int idx = blockIdx.x, tI = 0, rem = NTILE;
  while (idx >= rem) { idx -= rem; --rem; ++tI; }
  const int tJ = tI + idx;
  const bool diag = (tI == tJ);

  const int t   = threadIdx.x;
  const int w   = t >> 6;
  const int l   = t & 63;
  const int hf  = l >> 5;
  const int sub = l & 31;
  const int jb  = tJ * 128 + sub * 4;

  float ca[4] = {0.f, 0.f, 0.f, 0.f};

#pragma unroll
  for (int step = 0; step < 16; ++step) {
    const int r  = w * 32 + step * 2 + hf;
    const int gi = tI * 128 + r;
    f32x4 v = *(const f32x4*)(sim + (size_t)gi * NROW + jb);
    float e[4];
#pragma unroll
    for (int k = 0; k < 4; ++k) {
      e[k] = __expf(TEMP_SIM * v[k]);
      if (diag && (jb + k <= gi)) e[k] = 0.f;
      ca[k] += e[k];
    }
    float rp = e[0] + e[1] + e[2] + e[3];
#pragma unroll
    for (int off = 1; off < 32; off <<= 1) rp += __shfl_xor(rp, off);
    if (sub == 0) atomicAdd(&rsum[gi], rp);
  }

  __shared__ float colacc[8][128];
#pragma unroll
  for (int k = 0; k < 4; ++k) colacc[w * 2 + hf][sub * 4 + k] = ca[k];
  __syncthreads();
  if (t < 128) {
    float s = 0.f;
#pragma unroll
    for (int q = 0; q < 8; ++q) s += colacc[q][t];
    atomicAdd(&rsum[tJ * 128 + t], s);
  }

  __syncthreads();
  __shared__ bool last;
  if (t == 0) {
    __threadfence();
    last = (atomicAdd(cnt, 1u) == NPAIR - 1);
  }
  __syncthreads();
  if (!last) return;

  float s = 0.f;
  for (int i = t; i < NROW; i += 256) {
    const int jp = (i < B_SZ) ? i + B_SZ : i - B_SZ;
    const float pos = (jp >= i) ? sim[(size_t)i * NROW + jp]
                                : sim[(size_t)jp * NROW + i];
    const float rs = atomicAdd(&rsum[i], 0.f);
    s += logf(rs) - TEMP_SIM * pos;
  }
#pragma unroll
  for (int off = 1; off < 64; off <<= 1) s += __shfl_xor(s, off);
  __shared__ float r[4];
  if ((t & 63) == 0) r[t >> 6] = s;
  __syncthreads();
  if (t == 0) out[0] = (r[0] + r[1] + r[2] + r[3]) * (1.0f / NROW);
}

extern "C" void kernel_launch(void* const* d_in, const int* in_sizes, int n_in,
                              void* d_out, int out_size, void* d_ws, size_t ws_size,
                              hipStream_t stream) {
  const float* emb_i = (const float*)d_in[0];
  const float* emb_j = (const float*)d_in[1];
  float* out = (float*)d_out;

  char* ws = (char*)d_ws;
  unsigned char* rn = (unsigned char*)ws;                 // 32 MB (fp8)
  float* sim  = (float*)(ws + (size_t)NROW * D_K);        // 16 MB
  float* rsum = sim + (size_t)NROW * NROW;                // 8 KB
  unsigned int* cnt = (unsigned int*)(rsum + NROW);

  zero_sim_kernel<<<dim3(2048), dim3(512), 0, stream>>>(sim);
  norm_kernel<<<dim3(NROW), dim3(512), 0, stream>>>(emb_i, emb_j, rn, rsum, cnt);
  gemm_sim_kernel<<<dim3(SPLIT, HPAIR), dim3(256), 0, stream>>>(rn, sim, 0);
  gemm_sim_kernel<<<dim3(SPLIT, HPAIR), dim3(256), 0, stream>>>(rn, sim, HPAIR);
  loss_tile_kernel<<<dim3(NPAIR), dim3(256), 0, stream>>>(sim, rsum, cnt, out);
}

// Round 6
// 249.249 us; speedup vs baseline: 1.2093x; 1.1402x over previous
//
#include <hip/hip_runtime.h>
#include <hip/hip_bf16.h>
#include <math.h>

#define B_SZ   1024
#define NROW   2048      // 2B
#define D_K    16384     // 128*128
#define SPLIT  8
#define KSEG   (D_K / SPLIT)   // 2048
#define NTILE  16
#define NPAIR  136
// fp8 rows scaled by 16 each => sim holds 256 * true_sim.
#define TEMP_SIM (2.0f / 256.0f)

typedef float f32x4 __attribute__((ext_vector_type(4)));
typedef long  i64;
typedef long  i64x2 __attribute__((ext_vector_type(2)));

typedef __attribute__((address_space(1))) unsigned int GU32;
typedef __attribute__((address_space(3))) unsigned int LU32;

__device__ __forceinline__ void async16(const void* g, void* l) {
  __builtin_amdgcn_global_load_lds((GU32*)(g), (LU32*)(l), 16, 0, 0);
}

// ---------------------------------------------------------------------------
// rn GLOBAL layout (verified zero-conflict in r3/r5): row r is split into 64B
// K-segments. Subchunk s (k-bytes [8s,8s+8)), q=s&3, h=s>>2 stored at byte
// (q ^ ((r>>1)&3))*16 + h*8. gemm stages each 64B segment as one LDS "plane"
// row (64B row stride); fragment read = ONE ds_read_b128 per (row, segment)
// at row*64 + (quad^((col>>1)&3))*16, halves = the two 32k MFMA operands.
// Measured SQ_LDS_BANK_CONFLICT == 0 with exactly this read pattern.
// ---------------------------------------------------------------------------

// ---------------------------------------------------------------------------
// Kernel 1: per-row normalize -> fp8 e4m3 (x16) rn[2048][16384] in the
// block-permuted global layout; zero sim/rsum/cnt (r0 structure: folding the
// 16MB sim zeroing here measured cheaper than a separate dispatch).
// ---------------------------------------------------------------------------
__global__ __launch_bounds__(512) void norm_kernel(
    const float* __restrict__ emb_i, const float* __restrict__ emb_j,
    unsigned char* __restrict__ rn, float* __restrict__ sim,
    float* __restrict__ rsum, unsigned int* __restrict__ cnt)
{
  const int b = blockIdx.x;
  const int t = threadIdx.x;
  const int c = t & 31;        // column group (4 cols)
  const int g = t >> 5;        // row group (8 rows), 0..15

  ((f32x4*)sim)[(size_t)b * 512 + t] = (f32x4){0.f, 0.f, 0.f, 0.f};
  if (b == 0) {
    for (int k = t; k < NROW; k += 512) rsum[k] = 0.f;
    if (t == 0) *cnt = 0u;
  }

  const float* src = (b < B_SZ) ? (emb_i + (size_t)b * D_K)
                                : (emb_j + (size_t)(b - B_SZ) * D_K);

  f32x4 vals[8];
  f32x4 ss = (f32x4){0.f, 0.f, 0.f, 0.f};
#pragma unroll
  for (int mm = 0; mm < 8; ++mm) {
    f32x4 v = *(const f32x4*)(src + (size_t)(g * 8 + mm) * 128 + c * 4);
    vals[mm] = v;
    ss += v * v;
  }

  __shared__ f32x4 part[16][32];
  part[g][c] = ss;
  __syncthreads();
  f32x4 css = part[0][c];
#pragma unroll
  for (int gg = 1; gg < 16; ++gg) css += part[gg][c];

  f32x4 mcn, colz2;
#pragma unroll
  for (int k = 0; k < 4; ++k) {
    mcn[k] = fmaxf(sqrtf(css[k]), 1e-12f);
    colz2[k] = css[k] / (mcn[k] * mcn[k]);
  }
  float s = colz2[0] + colz2[1] + colz2[2] + colz2[3];
#pragma unroll
  for (int off = 1; off < 64; off <<= 1) s += __shfl_xor(s, off);
  const float rowfac = fmaxf(sqrtf(0.5f * s), 1e-8f);

  f32x4 scale;
#pragma unroll
  for (int k = 0; k < 4; ++k) scale[k] = 16.0f / (mcn[k] * rowfac);

  unsigned char* dst = rn + (size_t)b * D_K;
  const int wsel = (b >> 1) & 3;
#pragma unroll
  for (int mm = 0; mm < 8; ++mm) {
    f32x4 sv = vals[mm] * scale;
    int p = 0;
    p = __builtin_amdgcn_cvt_pk_fp8_f32(sv[0], sv[1], p, false);
    p = __builtin_amdgcn_cvt_pk_fp8_f32(sv[2], sv[3], p, true);
    // original k-byte index of this int: k = (g*8+mm)*128 + c*4
    const int k = (g * 8 + mm) * 128 + c * 4;
    // permute within the 64B segment: q=(k>>3)&3, h=(k>>5)&1
    const int nk = (k & ~63) | ((((k >> 3) & 3) ^ wsel) << 4)
                 | (((k >> 5) & 1) << 3) | (k & 7);
    *(int*)(dst + nk) = p;
  }
}

// ---------------------------------------------------------------------------
// Kernel 2: sim(upper) += rn @ rn^T. fp8 MFMA, 128x128 tile, BK=128,
// r0's PROVEN drain structure (sync / 8x global_load_lds / sync / 64 MFMA,
// 16 iters) + r3/r5's zero-conflict layout. SINGLE dispatch, grid
// (SPLIT, NPAIR) = 1088 blocks = 4.25/CU: r5 proved splitting into 2x544
// costs 26 us (tail imbalance + halved co-residency; occupancy 23->15%).
// Block co-residency (~3/CU: 32KB LDS, 76 VGPR) provides the latency hiding
// (m114) that explicit 2-phase pipelines failed to beat (r1/r2/r3).
// XCD = linear%8 owns one K-segment -> staging L2-resident (FETCH ~17MB).
// ---------------------------------------------------------------------------
__global__ __launch_bounds__(256) void gemm_sim_kernel(
    const unsigned char* __restrict__ rn, float* __restrict__ sim)
{
  int idx = blockIdx.y, tI = 0, rem = NTILE;
  while (idx >= rem) { idx -= rem; --rem; ++tI; }
  const int tJ = tI + idx;
  const bool diag = (tI == tJ);

  const int kBase = blockIdx.x * KSEG;
  const int t    = threadIdx.x;
  const int lane = t & 63;
  const int wave = t >> 6;
  const int wm = wave >> 1, wn = wave & 1;
  const int quad = lane >> 4, col = lane & 15;

  __shared__ __align__(16) unsigned char As[2][128 * 64];  // plane p = K-seg p
  __shared__ __align__(16) unsigned char Bs[2][128 * 64];

  // staging: instr (j,p) stages rows 64j..64j+63, segment p.
  // thread t -> row 64j+(t>>2), stored 16B chunk t&3 -> LDS plane p,
  // j*4096 + t*16 (lane-linear as global_load_lds requires).
  const int srow = t >> 2;
  const unsigned char* aGb = rn + (size_t)(tI * 128 + srow) * D_K + kBase + (t & 3) * 16;
  const unsigned char* bGb = rn + (size_t)(tJ * 128 + srow) * D_K + kBase + (t & 3) * 16;

  f32x4 acc[4][4];
#pragma unroll
  for (int mi = 0; mi < 4; ++mi)
#pragma unroll
    for (int ni = 0; ni < 4; ++ni)
      acc[mi][ni] = (f32x4){0.f, 0.f, 0.f, 0.f};

  // fragment-read 16B block: quad ^ ((row>>1)&3); row bits 1..2 come from col
  const int rblk = (quad ^ ((col >> 1) & 3)) * 16;

  for (int k0 = 0; k0 < KSEG; k0 += 128) {
    __syncthreads();   // previous compute done -> safe to overwrite
#pragma unroll
    for (int j = 0; j < 2; ++j)
#pragma unroll
      for (int p = 0; p < 2; ++p) {
        async16(aGb + (size_t)(64 * j) * D_K + k0 + p * 64,
                &As[p][j * 4096 + t * 16]);
        async16(bGb + (size_t)(64 * j) * D_K + k0 + p * 64,
                &Bs[p][j * 4096 + t * 16]);
      }
    __syncthreads();   // compiler emits vmcnt(0) drain before barrier

#pragma unroll
    for (int hh = 0; hh < 2; ++hh) {
      // one b128 per (row-fragment, segment): halves are k-steps 2hh, 2hh+1
      i64x2 av[4], bv[4];
#pragma unroll
      for (int mi = 0; mi < 4; ++mi)
        av[mi] = *(const i64x2*)(&As[hh][(wm * 64 + mi * 16 + col) * 64 + rblk]);
#pragma unroll
      for (int ni = 0; ni < 4; ++ni)
        bv[ni] = *(const i64x2*)(&Bs[hh][(wn * 64 + ni * 16 + col) * 64 + rblk]);

#pragma unroll
      for (int mi = 0; mi < 4; ++mi)
#pragma unroll
        for (int ni = 0; ni < 4; ++ni)
          acc[mi][ni] = __builtin_amdgcn_mfma_f32_16x16x32_fp8_fp8(
              av[mi][0], bv[ni][0], acc[mi][ni], 0, 0, 0);
#pragma unroll
      for (int mi = 0; mi < 4; ++mi)
#pragma unroll
        for (int ni = 0; ni < 4; ++ni)
          acc[mi][ni] = __builtin_amdgcn_mfma_f32_16x16x32_fp8_fp8(
              av[mi][1], bv[ni][1], acc[mi][ni], 0, 0, 0);
    }
  }

  // C/D layout: col=lane&15, row=quad*4+reg. Diag tiles: only j >= i stored.
  const int iB = tI * 128 + wm * 64;
  const int jB = tJ * 128 + wn * 64;
#pragma unroll
  for (int mi = 0; mi < 4; ++mi) {
#pragma unroll
    for (int reg = 0; reg < 4; ++reg) {
      const int i = iB + mi * 16 + quad * 4 + reg;
#pragma unroll
      for (int ni = 0; ni < 4; ++ni) {
        const int j = jB + ni * 16 + col;
        if (!diag || j >= i)
          atomicAdd(&sim[(size_t)i * NROW + j], acc[mi][ni][reg]);
      }
    }
  }
}

// ---------------------------------------------------------------------------
// Kernel 3: tile exp-sum (upper tiles, symmetric scatter) + fused finalize.
// r0's version (136 blocks, serial 16-step): measured faster in aggregate
// than the 1088-block variant (rsum atomic contention).
// ---------------------------------------------------------------------------
__global__ __launch_bounds__(256) void loss_tile_kernel(
    const float* __restrict__ sim, float* __restrict__ rsum,
    unsigned int* __restrict__ cnt, float* __restrict__ out)
{
  int idx = blockIdx.x, tI = 0, rem = NTILE;
  while (idx >= rem) { idx -= rem; --rem; ++tI; }
  const int tJ = tI + idx;
  const bool diag = (tI == tJ);

  const int t   = threadIdx.x;
  const int w   = t >> 6;
  const int l   = t & 63;
  const int hf  = l >> 5;
  const int sub = l & 31;
  const int jb  = tJ * 128 + sub * 4;

  float ca[4] = {0.f, 0.f, 0.f, 0.f};

#pragma unroll
  for (int step = 0; step < 16; ++step) {
    const int r  = w * 32 + step * 2 + hf;
    const int gi = tI * 128 + r;
    f32x4 v = *(const f32x4*)(sim + (size_t)gi * NROW + jb);
    float e[4];
#pragma unroll
    for (int k = 0; k < 4; ++k) {
      e[k] = __expf(TEMP_SIM * v[k]);
      if (diag && (jb + k <= gi)) e[k] = 0.f;
      ca[k] += e[k];
    }
    float rp = e[0] + e[1] + e[2] + e[3];
#pragma unroll
    for (int off = 1; off < 32; off <<= 1) rp += __shfl_xor(rp, off);
    if (sub == 0) atomicAdd(&rsum[gi], rp);
  }

  __shared__ float colacc[8][128];
#pragma unroll
  for (int k = 0; k < 4; ++k) colacc[w * 2 + hf][sub * 4 + k] = ca[k];
  __syncthreads();
  if (t < 128) {
    float s = 0.f;
#pragma unroll
    for (int q = 0; q < 8; ++q) s += colacc[q][t];
    atomicAdd(&rsum[tJ * 128 + t], s);
  }

  __syncthreads();
  __shared__ bool last;
  if (t == 0) {
    __threadfence();
    last = (atomicAdd(cnt, 1u) == NPAIR - 1);
  }
  __syncthreads();
  if (!last) return;

  float s = 0.f;
  for (int i = t; i < NROW; i += 256) {
    const int jp = (i < B_SZ) ? i + B_SZ : i - B_SZ;
    const float pos = (jp >= i) ? sim[(size_t)i * NROW + jp]
                                : sim[(size_t)jp * NROW + i];
    const float rs = atomicAdd(&rsum[i], 0.f);
    s += logf(rs) - TEMP_SIM * pos;
  }
#pragma unroll
  for (int off = 1; off < 64; off <<= 1) s += __shfl_xor(s, off);
  __shared__ float r[4];
  if ((t & 63) == 0) r[t >> 6] = s;
  __syncthreads();
  if (t == 0) out[0] = (r[0] + r[1] + r[2] + r[3]) * (1.0f / NROW);
}

extern "C" void kernel_launch(void* const* d_in, const int* in_sizes, int n_in,
                              void* d_out, int out_size, void* d_ws, size_t ws_size,
                              hipStream_t stream) {
  const float* emb_i = (const float*)d_in[0];
  const float* emb_j = (const float*)d_in[1];
  float* out = (float*)d_out;

  char* ws = (char*)d_ws;
  unsigned char* rn = (unsigned char*)ws;                 // 32 MB (fp8)
  float* sim  = (float*)(ws + (size_t)NROW * D_K);        // 16 MB
  float* rsum = sim + (size_t)NROW * NROW;                // 8 KB
  unsigned int* cnt = (unsigned int*)(rsum + NROW);

  norm_kernel<<<dim3(NROW), dim3(512), 0, stream>>>(emb_i, emb_j, rn, sim, rsum, cnt);
  gemm_sim_kernel<<<dim3(SPLIT, NPAIR), dim3(256), 0, stream>>>(rn, sim);
  loss_tile_kernel<<<dim3(NPAIR), dim3(256), 0, stream>>>(sim, rsum, cnt, out);
}